// Round 3
// baseline (294.909 us; speedup 1.0000x reference)
//
#include <hip/hip_runtime.h>
#include <hip/hip_bf16.h>

#define TOK 16384
#define HD  1024
#define DD  256
#define NE  8

typedef __attribute__((ext_vector_type(8))) short short8;
typedef __attribute__((ext_vector_type(4))) float floatx4;
typedef unsigned short u16;

static __device__ __forceinline__ float bf2f(u16 v) {
  union { unsigned int u; float f; } c; c.u = ((unsigned int)v) << 16; return c.f;
}
static __device__ __forceinline__ u16 f2bf(float f) {
  __hip_bfloat16 h = __float2bfloat16(f);
  return *reinterpret_cast<u16*>(&h);
}

// Load 8 consecutive elements as bf16 (canonical), from either a bf16 or fp32 tensor.
static __device__ __forceinline__ short8 load8bf(const void* base, size_t eoff, int isf32) {
  if (isf32) {
    const float* p = (const float*)base + eoff;
    float4 a = *(const float4*)p;
    float4 b = *(const float4*)(p + 4);
    u16 t[8] = {f2bf(a.x), f2bf(a.y), f2bf(a.z), f2bf(a.w),
                f2bf(b.x), f2bf(b.y), f2bf(b.z), f2bf(b.w)};
    return *(short8*)t;
  } else {
    return *(const short8*)((const u16*)base + eoff);
  }
}

// Load 16 consecutive elements at NATIVE precision into fp32 (router needs full precision).
static __device__ __forceinline__ void load16f(const void* base, size_t eoff, int isf32, float* out) {
  if (isf32) {
    const float* p = (const float*)base + eoff;
    float4 a = *(const float4*)p, b = *(const float4*)(p + 4);
    float4 c = *(const float4*)(p + 8), d = *(const float4*)(p + 12);
    out[0]=a.x; out[1]=a.y; out[2]=a.z; out[3]=a.w;
    out[4]=b.x; out[5]=b.y; out[6]=b.z; out[7]=b.w;
    out[8]=c.x; out[9]=c.y; out[10]=c.z; out[11]=c.w;
    out[12]=d.x; out[13]=d.y; out[14]=d.z; out[15]=d.w;
  } else {
    const u16* p = (const u16*)base + eoff;
    union { float4 v; u16 s[8]; } u0, u1;
    u0.v = *(const float4*)p;
    u1.v = *(const float4*)(p + 8);
    for (int j = 0; j < 8; ++j) { out[j] = bf2f(u0.s[j]); out[8 + j] = bf2f(u1.s[j]); }
  }
}

// ---- dtype detection (insurance; expected: all fp32 -> flags=1).
__global__ void detect_kernel(const u16* x, const u16* gw, const u16* wg,
                              const u16* wu, const u16* wd, int* flags) {
  const u16* ptrs[5] = {x, gw, wg, wu, wd};
  int lane = threadIdx.x;
  for (int i = 0; i < 5; ++i) {
    int cnt = 0;
    for (int j = 0; j < 8; ++j) {
      u16 w = ptrs[i][lane * 8 + j];
      int e = (w >> 7) & 0xFF;
      cnt += (e >= 154 || (e >= 1 && e <= 90)) ? 1 : 0;
    }
    for (int off = 32; off >= 1; off >>= 1) cnt += __shfl_xor(cnt, off, 64);
    if (lane == 0) flags[i] = (cnt >= 64) ? 1 : 0;
  }
}

// ---- weight transpose to canonical bf16, K-contiguous.
// wg,wu: [E][1024][256] -> [E][256][1024]; wd: [E][256][1024] -> [E][1024][256]
__global__ __launch_bounds__(256) void transpose_prep(
    const void* wg, const void* wu, const void* wd,
    u16* __restrict__ wgT, u16* __restrict__ wuT, u16* __restrict__ wdT,
    const int* __restrict__ flags) {
  __shared__ u16 tile[64][72];
  int bid = blockIdx.x;
  const void* src; u16* dst; int R, C, f;
  if (bid < 512)       { src = wg; dst = wgT; R = HD; C = DD; f = flags[2]; }
  else if (bid < 1024) { src = wu; dst = wuT; R = HD; C = DD; f = flags[3]; bid -= 512; }
  else                 { src = wd; dst = wdT; R = DD; C = HD; f = flags[4]; bid -= 1024; }
  int e = bid >> 6, t = bid & 63;
  int ntc = C >> 6;
  int tr = t / ntc, tc = t % ntc;

  int tid = threadIdx.x;
  int r = tid >> 2, c0 = (tid & 3) * 16;
  size_t so = (size_t)e * R * C + (size_t)(tr * 64 + r) * C + tc * 64 + c0;
  *(short8*)&tile[r][c0]     = load8bf(src, so, f);
  *(short8*)&tile[r][c0 + 8] = load8bf(src, so + 8, f);
  __syncthreads();
  int c = tid >> 2, r0 = (tid & 3) * 16;
  alignas(16) u16 buf[16];
  for (int j = 0; j < 16; ++j) buf[j] = tile[r0 + j][c];
  u16* d = dst + (size_t)e * R * C + (size_t)(tc * 64 + c) * R + tr * 64 + r0;
  *(float4*)(d)     = *(const float4*)&buf[0];
  *(float4*)(d + 8) = *(const float4*)&buf[8];
}

// ---- router: logits at NATIVE precision, argmax (first-max = np semantics), token lists.
__global__ __launch_bounds__(256) void router_kernel(
    const void* x, const void* gw, const int* __restrict__ flags,
    int* __restrict__ counts, int* __restrict__ tlist) {
  __shared__ int sexp[64];
  __shared__ int sbase[NE];
  int tid = threadIdx.x, lane = tid & 63, wave = tid >> 6;
  int tok0 = blockIdx.x * 64;
  int fx = flags[0], fg = flags[1];

  for (int i = 0; i < 16; ++i) {
    int t = tok0 + wave * 16 + i;
    float xa[16];
    load16f(x, (size_t)t * HD + lane * 16, fx, xa);
    float acc[NE];
    for (int e = 0; e < NE; ++e) {
      float ga[16];
      load16f(gw, (size_t)e * HD + lane * 16, fg, ga);
      float a = 0.f;
      for (int j = 0; j < 16; ++j) a += xa[j] * ga[j];
      acc[e] = a;
    }
    for (int off = 32; off >= 1; off >>= 1)
      for (int e = 0; e < NE; ++e) acc[e] += __shfl_xor(acc[e], off, 64);
    if (lane == 0) {
      int be = 0; float bv = acc[0];
      for (int e = 1; e < NE; ++e) if (acc[e] > bv) { bv = acc[e]; be = e; }
      sexp[wave * 16 + i] = be;
    }
  }
  __syncthreads();
  if (tid < NE) {
    int c = 0;
    for (int i = 0; i < 64; ++i) c += (sexp[i] == tid) ? 1 : 0;
    sbase[tid] = c ? atomicAdd(&counts[tid], c) : 0;
  }
  __syncthreads();
  if (tid < 64) {
    int e = sexp[tid], rank = 0;
    for (int i = 0; i < tid; ++i) rank += (sexp[i] == e) ? 1 : 0;
    tlist[e * TOK + sbase[e] + rank] = tok0 + tid;
  }
}

// ---- fused FFN: stage1 (x@wgT, x@wuT -> relu(g)^2*u in LDS), stage2 (inter@wdT -> out).
// 64-token tile per block. inter never touches HBM. Output fp32.
__global__ __launch_bounds__(256) void fused_ffn(
    const void* x, const u16* __restrict__ wgT, const u16* __restrict__ wuT,
    const u16* __restrict__ wdT, const int* __restrict__ flags,
    const int* __restrict__ counts, const int* __restrict__ tlist,
    float* __restrict__ out) {
  int e = blockIdx.y;
  int cnt = counts[e];
  int row0 = blockIdx.x * 64;
  if (row0 >= cnt) return;

  __shared__ int stok[64];
  __shared__ u16 xA[64][40];    // stage-1 A staging (32 K-elems + pad 8)
  __shared__ u16 sB[256][40];   // B staging; reused as float st[16][132] in stage-2 epilogue
  __shared__ u16 sI[64][264];   // inter tile, bf16, +8 pad

  int tid = threadIdx.x, lane = tid & 63, wave = tid >> 6;
  int fx = flags[0];
  if (tid < 64) {
    int r = row0 + tid;
    stok[tid] = tlist[e * TOK + (r < cnt ? r : cnt - 1)];
  }
  __syncthreads();
  int rmax = cnt - row0; if (rmax > 64) rmax = 64;

  int col = lane & 15, quad = lane >> 4;
  int at = tid >> 2, ac = (tid & 3) * 8;
  size_t axoff = (size_t)stok[at] * HD + ac;

  // ---------- stage 1: two passes over K=1024 (p=0: gate, p=1: up)
  for (int p = 0; p < 2; ++p) {
    const u16* W = p ? wuT : wgT;
    floatx4 acc[4][4];
    floatx4 zz = {0.f, 0.f, 0.f, 0.f};
    for (int m = 0; m < 4; ++m) for (int j = 0; j < 4; ++j) acc[m][j] = zz;

    for (int k0 = 0; k0 < HD; k0 += 32) {
      short8 av = load8bf(x, axoff + k0, fx);
      short8 bv[4];
      for (int i = 0; i < 4; ++i) {
        int id = i * 256 + tid;
        int n = id >> 2, c = (id & 3) * 8;
        bv[i] = *(const short8*)(W + ((size_t)e * DD + n) * HD + k0 + c);
      }
      __syncthreads();
      *(short8*)&xA[at][ac] = av;
      for (int i = 0; i < 4; ++i) {
        int id = i * 256 + tid;
        *(short8*)&sB[id >> 2][(id & 3) * 8] = bv[i];
      }
      __syncthreads();
      short8 af[4], bfr[4];
      for (int m = 0; m < 4; ++m) af[m] = *(const short8*)&xA[m * 16 + col][quad * 8];
      for (int j = 0; j < 4; ++j) bfr[j] = *(const short8*)&sB[wave * 64 + j * 16 + col][quad * 8];
      for (int m = 0; m < 4; ++m)
        for (int j = 0; j < 4; ++j)
          acc[m][j] = __builtin_amdgcn_mfma_f32_16x16x32_bf16(af[m], bfr[j], acc[m][j], 0, 0, 0);
    }
    // epilogue into sI (same-lane RMW between passes; no extra sync needed)
    for (int m = 0; m < 4; ++m)
      for (int j = 0; j < 4; ++j)
        for (int r = 0; r < 4; ++r) {
          int ri = m * 16 + quad * 4 + r;          // C layout: row=quad*4+reg
          int ci = wave * 64 + j * 16 + col;       //           col=lane&15
          if (p == 0) {
            float g = acc[m][j][r]; g = g > 0.f ? g : 0.f;
            sI[ri][ci] = f2bf(g * g);
          } else {
            sI[ri][ci] = f2bf(bf2f(sI[ri][ci]) * acc[m][j][r]);
          }
        }
  }
  __syncthreads();   // sI complete; stage 2 reads it cross-lane

  // ---------- stage 2: inter(64x256) @ wdT(256x1024), 8 chunks of 128 cols
  float (*st)[132] = (float(*)[132])sB;   // 16*132*4 = 8448 B <= sizeof(sB)
  for (int nc = 0; nc < 8; ++nc) {
    int n0 = nc * 128;
    floatx4 a2[4][2];
    floatx4 zz = {0.f, 0.f, 0.f, 0.f};
    for (int m = 0; m < 4; ++m) for (int j = 0; j < 2; ++j) a2[m][j] = zz;

    for (int k0 = 0; k0 < DD; k0 += 32) {
      short8 bv[2];
      for (int i = 0; i < 2; ++i) {
        int id = i * 256 + tid;
        int n = id >> 2, c = (id & 3) * 8;
        bv[i] = *(const short8*)(wdT + ((size_t)e * HD + n0 + n) * DD + k0 + c);
      }
      __syncthreads();   // prior epilogue/frag reads of sB done
      for (int i = 0; i < 2; ++i) {
        int id = i * 256 + tid;
        *(short8*)&sB[id >> 2][(id & 3) * 8] = bv[i];
      }
      __syncthreads();
      short8 af[4], bfr[2];
      for (int m = 0; m < 4; ++m) af[m] = *(const short8*)&sI[m * 16 + col][k0 + quad * 8];
      for (int j = 0; j < 2; ++j) bfr[j] = *(const short8*)&sB[wave * 32 + j * 16 + col][quad * 8];
      for (int m = 0; m < 4; ++m)
        for (int j = 0; j < 2; ++j)
          a2[m][j] = __builtin_amdgcn_mfma_f32_16x16x32_bf16(af[m], bfr[j], a2[m][j], 0, 0, 0);
    }
    // epilogue: stage 16 rows x 128 fp32 cols through LDS (reusing sB) for 512B/row stores
    for (int m = 0; m < 4; ++m) {
      __syncthreads();   // K-loop sB frag reads (m=0) / prior store reads (m>0) done
      for (int j = 0; j < 2; ++j)
        for (int r = 0; r < 4; ++r)
          st[quad * 4 + r][wave * 32 + j * 16 + col] = a2[m][j][r];
      __syncthreads();
      int rr = tid >> 4, cc = (tid & 15) * 8;
      int row = m * 16 + rr;
      if (row < rmax) {
        float* op = out + (size_t)stok[row] * HD + n0 + cc;
        *(float4*)op       = *(const float4*)&st[rr][cc];
        *(float4*)(op + 4) = *(const float4*)&st[rr][cc + 4];
      }
    }
  }
}

// ---------------- launch ---------------------------------------------------
extern "C" void kernel_launch(void* const* d_in, const int* in_sizes, int n_in,
                              void* d_out, int out_size, void* d_ws, size_t ws_size,
                              hipStream_t stream) {
  const void* x  = d_in[0];
  const void* gw = d_in[1];
  const void* wg = d_in[2];
  const void* wu = d_in[3];
  const void* wd = d_in[4];
  float* out = (float*)d_out;

  char* ws = (char*)d_ws;
  int* flags  = (int*)ws;                       // 64 B
  int* counts = (int*)(ws + 64);                // 32 B (pad to 256)
  int* tlist  = (int*)(ws + 256);               // 512 KB
  u16* wgT = (u16*)(ws + 524544);               // 4 MB
  u16* wuT = wgT + (size_t)NE * DD * HD;        // 4 MB
  u16* wdT = wuT + (size_t)NE * DD * HD;        // 4 MB; total ~12.5 MiB

  hipMemsetAsync(counts, 0, NE * sizeof(int), stream);
  detect_kernel<<<1, 64, 0, stream>>>((const u16*)x, (const u16*)gw, (const u16*)wg,
                                      (const u16*)wu, (const u16*)wd, flags);
  transpose_prep<<<1536, 256, 0, stream>>>(wg, wu, wd, wgT, wuT, wdT, flags);
  router_kernel<<<TOK / 64, 256, 0, stream>>>(x, gw, flags, counts, tlist);
  fused_ffn<<<dim3(TOK / 64, NE), 256, 0, stream>>>(x, wgT, wuT, wdT, flags, counts, tlist, out);
}

// Round 4
// 225.573 us; speedup vs baseline: 1.3074x; 1.3074x over previous
//
#include <hip/hip_runtime.h>
#include <hip/hip_bf16.h>

#define TOK 16384
#define HD  1024
#define DD  256
#define NE  8

typedef __attribute__((ext_vector_type(8))) short short8;
typedef __attribute__((ext_vector_type(4))) float floatx4;
typedef unsigned short u16;

static __device__ __forceinline__ u16 f2bf(float f) {
  __hip_bfloat16 h = __float2bfloat16(f);
  return *reinterpret_cast<u16*>(&h);
}
// convert 8 consecutive fp32 (16B-aligned) -> bf16 short8
static __device__ __forceinline__ short8 cvt8(const float* p) {
  float4 a = *(const float4*)p;
  float4 b = *(const float4*)(p + 4);
  u16 t[8] = {f2bf(a.x), f2bf(a.y), f2bf(a.z), f2bf(a.w),
              f2bf(b.x), f2bf(b.y), f2bf(b.z), f2bf(b.w)};
  return *(short8*)t;
}

// ---- prep: weight transpose->bf16 (blocks 0..1535) + router (blocks 1536..1791)
// wg,wu: [E][1024][256] -> bf16 [E][256][1024]; wd: [E][256][1024] -> bf16 [E][1024][256]
__global__ __launch_bounds__(256) void prep_kernel(
    const float* __restrict__ wg, const float* __restrict__ wu,
    const float* __restrict__ wd, const float* __restrict__ x,
    const float* __restrict__ gw,
    u16* __restrict__ wgT, u16* __restrict__ wuT, u16* __restrict__ wdT,
    int* __restrict__ counts, int* __restrict__ tlist)
{
  __shared__ u16 tile[64][72];
  __shared__ int sexp[64];
  __shared__ int sbase[NE];
  int bid = blockIdx.x;
  int tid = threadIdx.x;

  if (bid < 1536) {
    const float* src; u16* dst; int R, C;
    if (bid < 512)       { src = wg; dst = wgT; R = HD; C = DD; }
    else if (bid < 1024) { src = wu; dst = wuT; R = HD; C = DD; bid -= 512; }
    else                 { src = wd; dst = wdT; R = DD; C = HD; bid -= 1024; }
    int e = bid >> 6, t = bid & 63;
    int ntc = C >> 6;
    int tr = t / ntc, tc = t % ntc;
    int r = tid >> 2, c0 = (tid & 3) * 16;
    const float* s = src + (size_t)e * R * C + (size_t)(tr * 64 + r) * C + tc * 64 + c0;
    *(short8*)&tile[r][c0]     = cvt8(s);
    *(short8*)&tile[r][c0 + 8] = cvt8(s + 8);
    __syncthreads();
    int c = tid >> 2, r0 = (tid & 3) * 16;
    alignas(16) u16 buf[16];
    for (int j = 0; j < 16; ++j) buf[j] = tile[r0 + j][c];
    u16* d = dst + (size_t)e * R * C + (size_t)(tc * 64 + c) * R + tr * 64 + r0;
    *(float4*)(d)     = *(const float4*)&buf[0];
    *(float4*)(d + 8) = *(const float4*)&buf[8];
    return;
  }

  // ---- router part: 64 tokens per block, fp32-exact logits, first-max argmax
  int lane = tid & 63, wave = tid >> 6;
  int tok0 = (bid - 1536) * 64;
  for (int i = 0; i < 16; ++i) {
    int t = tok0 + wave * 16 + i;
    const float* xp = x + (size_t)t * HD + lane * 16;
    float4 x0 = *(const float4*)xp,       x1 = *(const float4*)(xp + 4);
    float4 x2 = *(const float4*)(xp + 8), x3 = *(const float4*)(xp + 12);
    float acc[NE];
    for (int e = 0; e < NE; ++e) {
      const float* gp = gw + e * HD + lane * 16;
      float4 g0 = *(const float4*)gp,       g1 = *(const float4*)(gp + 4);
      float4 g2 = *(const float4*)(gp + 8), g3 = *(const float4*)(gp + 12);
      acc[e] = x0.x*g0.x + x0.y*g0.y + x0.z*g0.z + x0.w*g0.w
             + x1.x*g1.x + x1.y*g1.y + x1.z*g1.z + x1.w*g1.w
             + x2.x*g2.x + x2.y*g2.y + x2.z*g2.z + x2.w*g2.w
             + x3.x*g3.x + x3.y*g3.y + x3.z*g3.z + x3.w*g3.w;
    }
    for (int off = 32; off >= 1; off >>= 1)
      for (int e = 0; e < NE; ++e) acc[e] += __shfl_xor(acc[e], off, 64);
    if (lane == 0) {
      int be = 0; float bv = acc[0];
      for (int e = 1; e < NE; ++e) if (acc[e] > bv) { bv = acc[e]; be = e; }
      sexp[wave * 16 + i] = be;
    }
  }
  __syncthreads();
  if (tid < NE) {
    int c = 0;
    for (int i = 0; i < 64; ++i) c += (sexp[i] == tid) ? 1 : 0;
    sbase[tid] = c ? atomicAdd(&counts[tid], c) : 0;
  }
  __syncthreads();
  if (tid < 64) {
    int e = sexp[tid], rank = 0;
    for (int i = 0; i < tid; ++i) rank += (sexp[i] == e) ? 1 : 0;
    tlist[e * TOK + sbase[e] + rank] = tok0 + tid;
  }
}

// ---- gemm1: gathered x(fp32->bf16) @ [g-half ++ u-half], epilogue relu(g)^2*u -> inter bf16
// flat grid 4096: e=bid&7 (XCD locality), half=(bid>>3)&1 (d cols 128), tile=bid>>4 (64 tokens)
__global__ __launch_bounds__(256) void gemm1_kernel(
    const float* __restrict__ x, const u16* __restrict__ wgT,
    const u16* __restrict__ wuT,
    const int* __restrict__ counts, const int* __restrict__ tlist,
    u16* __restrict__ inter)
{
  int bid = blockIdx.x;
  int e = bid & 7, half = (bid >> 3) & 1, tile = bid >> 4;
  int cnt = counts[e];
  int row0 = tile * 64;
  if (row0 >= cnt) return;

  __shared__ int stok[64];
  __shared__ u16 xA[64][40];
  __shared__ u16 sB[256][40];

  int tid = threadIdx.x, lane = tid & 63, wave = tid >> 6;
  if (tid < 64) {
    int r = row0 + tid;
    stok[tid] = tlist[e * TOK + (r < cnt ? r : cnt - 1)];
  }
  __syncthreads();
  int rmax = cnt - row0; if (rmax > 64) rmax = 64;

  int col = lane & 15, quad = lane >> 4;
  int at = tid >> 2, ac = (tid & 3) * 8;
  const float* axp = x + (size_t)stok[at] * HD + ac;

  const u16* bp[4];
  for (int i = 0; i < 4; ++i) {
    int id = i * 256 + tid;
    int n = id >> 2, c = (id & 3) * 8;
    const u16* base = (n < 128) ? (wgT + ((size_t)e * DD + half * 128 + n) * HD)
                                : (wuT + ((size_t)e * DD + half * 128 + (n - 128)) * HD);
    bp[i] = base + c;
  }

  floatx4 acc[4][4];
  floatx4 zz = {0.f, 0.f, 0.f, 0.f};
  for (int m = 0; m < 4; ++m) for (int j = 0; j < 4; ++j) acc[m][j] = zz;

  for (int k0 = 0; k0 < HD; k0 += 32) {
    short8 av = cvt8(axp + k0);
    short8 bv[4];
    for (int i = 0; i < 4; ++i) bv[i] = *(const short8*)(bp[i] + k0);
    __syncthreads();
    *(short8*)&xA[at][ac] = av;
    for (int i = 0; i < 4; ++i) {
      int id = i * 256 + tid;
      *(short8*)&sB[id >> 2][(id & 3) * 8] = bv[i];
    }
    __syncthreads();
    short8 af[4], bfr[4];
    for (int m = 0; m < 4; ++m) af[m] = *(const short8*)&xA[m * 16 + col][quad * 8];
    bfr[0] = *(const short8*)&sB[wave * 32 + col][quad * 8];
    bfr[1] = *(const short8*)&sB[wave * 32 + 16 + col][quad * 8];
    bfr[2] = *(const short8*)&sB[128 + wave * 32 + col][quad * 8];
    bfr[3] = *(const short8*)&sB[128 + wave * 32 + 16 + col][quad * 8];
    for (int m = 0; m < 4; ++m)
      for (int j = 0; j < 4; ++j)
        acc[m][j] = __builtin_amdgcn_mfma_f32_16x16x32_bf16(af[m], bfr[j], acc[m][j], 0, 0, 0);
  }

  for (int m = 0; m < 4; ++m)
    for (int jj = 0; jj < 2; ++jj)
      for (int r = 0; r < 4; ++r) {
        int row = m * 16 + quad * 4 + r;     // C layout: col=lane&15, row=quad*4+reg
        if (row < rmax) {
          float g = acc[m][jj][r]; g = g > 0.f ? g : 0.f;
          float u = acc[m][jj + 2][r];
          inter[(size_t)stok[row] * DD + half * 128 + wave * 32 + jj * 16 + col] = f2bf(g * g * u);
        }
      }
}

// ---- gemm2: gathered inter(bf16) @ wdT -> out fp32 (LDS-staged coalesced stores)
// flat grid 8192: e=bid&7, q=(bid>>3)&3 (256-col quarter), tile=bid>>5 (64 tokens)
__global__ __launch_bounds__(256) void gemm2_kernel(
    const u16* __restrict__ inter, const u16* __restrict__ wdT,
    const int* __restrict__ counts, const int* __restrict__ tlist,
    float* __restrict__ out)
{
  int bid = blockIdx.x;
  int e = bid & 7, q = (bid >> 3) & 3, tile = bid >> 5;
  int cnt = counts[e];
  int row0 = tile * 64;
  if (row0 >= cnt) return;
  int n0 = q * 256;

  __shared__ int stok[64];
  __shared__ u16 sA[64][40];
  __shared__ __align__(16) u16 sBraw[256 * 40];   // 20480 B; reused as float st[16][260]
  u16 (*sB)[40] = (u16(*)[40])sBraw;
  float (*st)[260] = (float(*)[260])sBraw;        // 16*260*4 = 16640 B

  int tid = threadIdx.x, lane = tid & 63, wave = tid >> 6;
  if (tid < 64) {
    int r = row0 + tid;
    stok[tid] = tlist[e * TOK + (r < cnt ? r : cnt - 1)];
  }
  __syncthreads();
  int rmax = cnt - row0; if (rmax > 64) rmax = 64;

  int col = lane & 15, quad = lane >> 4;
  int at = tid >> 2, ac = (tid & 3) * 8;
  const u16* aip = inter + (size_t)stok[at] * DD + ac;

  floatx4 acc[4][4];
  floatx4 zz = {0.f, 0.f, 0.f, 0.f};
  for (int m = 0; m < 4; ++m) for (int j = 0; j < 4; ++j) acc[m][j] = zz;

  for (int k0 = 0; k0 < DD; k0 += 32) {
    short8 av = *(const short8*)(aip + k0);
    short8 bv[4];
    for (int i = 0; i < 4; ++i) {
      int id = i * 256 + tid;
      int n = id >> 2, c = (id & 3) * 8;
      bv[i] = *(const short8*)(wdT + ((size_t)e * HD + n0 + n) * DD + k0 + c);
    }
    __syncthreads();
    *(short8*)&sA[at][ac] = av;
    for (int i = 0; i < 4; ++i) {
      int id = i * 256 + tid;
      *(short8*)&sB[id >> 2][(id & 3) * 8] = bv[i];
    }
    __syncthreads();
    short8 af[4], bfr[4];
    for (int m = 0; m < 4; ++m) af[m] = *(const short8*)&sA[m * 16 + col][quad * 8];
    for (int j = 0; j < 4; ++j) bfr[j] = *(const short8*)&sB[wave * 64 + j * 16 + col][quad * 8];
    for (int m = 0; m < 4; ++m)
      for (int j = 0; j < 4; ++j)
        acc[m][j] = __builtin_amdgcn_mfma_f32_16x16x32_bf16(af[m], bfr[j], acc[m][j], 0, 0, 0);
  }

  // epilogue: 16 rows x 256 fp32 at a time through LDS -> 1KB/row coalesced stores
  for (int m = 0; m < 4; ++m) {
    __syncthreads();
    for (int j = 0; j < 4; ++j)
      for (int r = 0; r < 4; ++r)
        st[quad * 4 + r][wave * 64 + j * 16 + col] = acc[m][j][r];
    __syncthreads();
    for (int i = 0; i < 4; ++i) {
      int id = i * 256 + tid;
      int r = id >> 6, c4 = (id & 63) * 4;
      int row = m * 16 + r;
      if (row < rmax)
        *(float4*)(out + (size_t)stok[row] * HD + n0 + c4) = *(const float4*)&st[r][c4];
    }
  }
}

// ---------------- launch ---------------------------------------------------
extern "C" void kernel_launch(void* const* d_in, const int* in_sizes, int n_in,
                              void* d_out, int out_size, void* d_ws, size_t ws_size,
                              hipStream_t stream) {
  const float* x  = (const float*)d_in[0];
  const float* gw = (const float*)d_in[1];
  const float* wg = (const float*)d_in[2];
  const float* wu = (const float*)d_in[3];
  const float* wd = (const float*)d_in[4];
  float* out = (float*)d_out;

  char* ws = (char*)d_ws;
  int* counts = (int*)ws;                        // 256 B
  int* tlist  = (int*)(ws + 256);                // 512 KB
  u16* wgT   = (u16*)(ws + 524544);              // 4 MB
  u16* wuT   = wgT + (size_t)NE * DD * HD;       // 4 MB
  u16* wdT   = wuT + (size_t)NE * DD * HD;       // 4 MB
  u16* inter = wdT + (size_t)NE * HD * DD;       // 8 MB; total ~20.5 MiB

  hipMemsetAsync(counts, 0, NE * sizeof(int), stream);
  prep_kernel<<<1792, 256, 0, stream>>>(wg, wu, wd, x, gw, wgT, wuT, wdT, counts, tlist);
  gemm1_kernel<<<4096, 256, 0, stream>>>(x, wgT, wuT, counts, tlist, inter);
  gemm2_kernel<<<8192, 256, 0, stream>>>(inter, wdT, counts, tlist, out);
}